// Round 5
// baseline (490.621 us; speedup 1.0000x reference)
//
#include <hip/hip_runtime.h>
#include <math.h>

#define B_ROWS   1024
#define IN_FEAT  76800
#define OUT_FEAT 10
#define NF4      (IN_FEAT / 4)        // 19200 dword-groups (4 elems) per row
#define W_ELEMS  (OUT_FEAT * IN_FEAT) // 768000
#define EPSQ     1e-5f
#define NLDS     3840                 // float4 cached in LDS (60 KB = first 20% of row)

// ---------------- K1: per-block partial sums of |W| ----------------
__global__ __launch_bounds__(256) void k_wabs_partial(const float* __restrict__ W,
                                                      float* __restrict__ partials) {
    const int tid = threadIdx.x, bid = blockIdx.x;
    float s = 0.f;
    for (int i = bid * 256 + tid; i < W_ELEMS; i += 256 * 256) s += fabsf(W[i]);
    #pragma unroll
    for (int off = 32; off >= 1; off >>= 1) s += __shfl_down(s, off, 64);
    __shared__ float red[4];
    const int wv = tid >> 6, ln = tid & 63;
    if (ln == 0) red[wv] = s;
    __syncthreads();
    if (tid == 0) partials[bid] = red[0] + red[1] + red[2] + red[3];
}

// ---------------- K2: final reduce -> scale_w = 1/clip(mean|W|, eps) ----------------
__global__ __launch_bounds__(256) void k_wscale(const float* __restrict__ partials,
                                                float* __restrict__ scale_w) {
    const int tid = threadIdx.x;
    float s = partials[tid];
    #pragma unroll
    for (int off = 32; off >= 1; off >>= 1) s += __shfl_down(s, off, 64);
    __shared__ float red[4];
    const int wv = tid >> 6, ln = tid & 63;
    if (ln == 0) red[wv] = s;
    __syncthreads();
    if (tid == 0) {
        float mean = (red[0] + red[1] + red[2] + red[3]) / (float)W_ELEMS;
        scale_w[0] = 1.0f / fmaxf(mean, EPSQ);
    }
}

// ---------------- K3: ternary-quantize weights into int8 dot4 planes ----------------
// wq[o * NF4 + k4] = 4 consecutive ternary weights (values -1/0/1 as signed bytes)
// of output o, inputs 4*k4 .. 4*k4+3. 10 planes x 76800 B = 768 KB, L2-resident.
__global__ __launch_bounds__(256) void k_wpack8(const float* __restrict__ W,
                                                const float* __restrict__ scale_w,
                                                unsigned int* __restrict__ wq) {
    const int k4 = blockIdx.x * 256 + threadIdx.x;
    if (k4 >= NF4) return;
    const float s = scale_w[0];
    #pragma unroll
    for (int o = 0; o < OUT_FEAT; ++o) {
        const float4 w4 = *(const float4*)(W + (size_t)o * IN_FEAT + 4 * (size_t)k4);
        int c0 = (int)fminf(1.f, fmaxf(-1.f, rintf(w4.x * s)));
        int c1 = (int)fminf(1.f, fmaxf(-1.f, rintf(w4.y * s)));
        int c2 = (int)fminf(1.f, fmaxf(-1.f, rintf(w4.z * s)));
        int c3 = (int)fminf(1.f, fmaxf(-1.f, rintf(w4.w * s)));
        unsigned int p = ((unsigned)(c0 & 0xFF)) | ((unsigned)(c1 & 0xFF) << 8) |
                         ((unsigned)(c2 & 0xFF) << 16) | ((unsigned)(c3 & 0xFF) << 24);
        wq[(size_t)o * NF4 + k4] = p;
    }
}

// ---------------- int8 x int8 dot4 with fp fallback ----------------
__device__ __forceinline__ int dot4(int a, int b, int c) {
#if __has_builtin(__builtin_amdgcn_sdot4)
    return __builtin_amdgcn_sdot4(a, b, c, false);
#else
    int a0 = (a << 24) >> 24, a1 = (a << 16) >> 24, a2 = (a << 8) >> 24, a3 = a >> 24;
    int b0 = (b << 24) >> 24, b1 = (b << 16) >> 24, b2 = (b << 8) >> 24, b3 = b >> 24;
    return c + a0 * b0 + a1 * b1 + a2 * b2 + a3 * b3;
#endif
}

__device__ __forceinline__ int packq(float4 v, float sx) {
    // |x*sx| <= 127*(1+2eps) -> rint lands in [-127,127], clamp provably unneeded
    int q0 = (int)rintf(v.x * sx);
    int q1 = (int)rintf(v.y * sx);
    int q2 = (int)rintf(v.z * sx);
    int q3 = (int)rintf(v.w * sx);
    return (int)(((unsigned)(q0 & 0xFF)) | ((unsigned)(q1 & 0xFF) << 8) |
                 ((unsigned)(q2 & 0xFF) << 16) | ((unsigned)(q3 & 0xFF) << 24));
}

// ---------------- main: one block per row, two-phase (absmax, then int8 GEMV) ----------
// Phase-2 x re-read is served by L3 (in-flight rows ~154 MB << 256 MB) + 60 KB LDS
// cache. Default VGPR allocation (no reg row cache, no occupancy attributes).
// R1/R2: reg cache spilled (716 MB scratch). R3: waves_per_eu(4,4) -> post-replay
// corruption, dropped. R4: fp decode+fma inner loop ~40 ops/elem -> VALU-heavy;
// this round: sdot4 inner loop ~6 ops/elem, integer-exact.
__global__ __launch_bounds__(1024) void k_main(const float* __restrict__ x,
                                               const unsigned int* __restrict__ wq,
                                               const float* __restrict__ bias,
                                               const float* __restrict__ scale_w,
                                               float* __restrict__ out) {
    __shared__ float4 xlds[NLDS];        // 60 KB cache of the row's first 3840 float4s
    __shared__ float  redmax[16];
    __shared__ int    racc[16][OUT_FEAT];
    __shared__ int    fin[OUT_FEAT];
    __shared__ float  lgs[OUT_FEAT];
    __shared__ float  sx_sh;

    const int tid = threadIdx.x;
    const int row = blockIdx.x;
    const float sw = scale_w[0];
    const float4* __restrict__ xrow = (const float4*)(x + (size_t)row * IN_FEAT);

    // ---- phase 1: stream row, compute absmax, cache first 60 KB in LDS ----
    float mx = 0.f;
    #pragma unroll
    for (int j = 0; j < 19; ++j) {
        int idx = tid + j * 1024;
        if (idx < NF4) {
            float4 v = xrow[idx];
            if (idx < NLDS) xlds[idx] = v;
            mx = fmaxf(mx, fmaxf(fmaxf(fabsf(v.x), fabsf(v.y)), fmaxf(fabsf(v.z), fabsf(v.w))));
        }
    }
    #pragma unroll
    for (int off = 32; off >= 1; off >>= 1) mx = fmaxf(mx, __shfl_down(mx, off, 64));
    const int wv = tid >> 6, ln = tid & 63;
    if (ln == 0) redmax[wv] = mx;
    __syncthreads();
    if (tid == 0) {
        float m = redmax[0];
        #pragma unroll
        for (int i = 1; i < 16; ++i) m = fmaxf(m, redmax[i]);
        sx_sh = 127.0f / fmaxf(m, EPSQ);
    }
    __syncthreads();
    const float sx = sx_sh;

    // ---- phase 2: re-read row (LDS / L3), quantize to int8, dot4 GEMV ----
    int acc[OUT_FEAT] = {0, 0, 0, 0, 0, 0, 0, 0, 0, 0};
    #pragma unroll
    for (int j = 0; j < 19; ++j) {
        int idx = tid + j * 1024;
        if (idx < NF4) {
            float4 v = (idx < NLDS) ? xlds[idx] : xrow[idx];
            int pk = packq(v, sx);
            #pragma unroll
            for (int o = 0; o < OUT_FEAT; ++o)
                acc[o] = dot4(pk, (int)wq[(size_t)o * NF4 + idx], acc[o]);
        }
    }

    // ---- phase 3: block reduce 10 int accumulators ----
    #pragma unroll
    for (int t = 0; t < OUT_FEAT; ++t) {
        int s = acc[t];
        #pragma unroll
        for (int off = 32; off >= 1; off >>= 1) s += __shfl_down(s, off, 64);
        if (ln == 0) racc[wv][t] = s;
    }
    __syncthreads();
    if (tid < OUT_FEAT) {
        int s = 0;
        #pragma unroll
        for (int w2 = 0; w2 < 16; ++w2) s += racc[w2][tid];
        fin[tid] = s;
    }
    __syncthreads();
    if (tid < OUT_FEAT) {
        // dequant: logits = acc / (sx*sw) + bias
        float inv = 1.0f / (sx * sw);
        lgs[tid] = (float)fin[tid] * inv + bias[tid];
    }
    __syncthreads();
    if (tid < OUT_FEAT) {
        float m = lgs[0];
        #pragma unroll
        for (int o = 1; o < OUT_FEAT; ++o) m = fmaxf(m, lgs[o]);
        float den = 0.f;
        #pragma unroll
        for (int o = 0; o < OUT_FEAT; ++o) den += __expf(lgs[o] - m);
        float e = __expf(lgs[tid] - m);
        out[row * OUT_FEAT + tid] = e / den;
    }
}

extern "C" void kernel_launch(void* const* d_in, const int* in_sizes, int n_in,
                              void* d_out, int out_size, void* d_ws, size_t ws_size,
                              hipStream_t stream) {
    const float* x    = (const float*)d_in[0];
    const float* Wmat = (const float*)d_in[1];
    const float* bias = (const float*)d_in[2];
    float* out = (float*)d_out;

    char* wsb = (char*)d_ws;
    float* scale_w        = (float*)wsb;                 // 1 float
    float* partials       = (float*)(wsb + 256);         // 256 floats
    unsigned int* wq      = (unsigned int*)(wsb + 4096); // 10 x 19200 dwords = 768 KB

    k_wabs_partial<<<256, 256, 0, stream>>>(Wmat, partials);
    k_wscale<<<1, 256, 0, stream>>>(partials, scale_w);
    k_wpack8<<<(NF4 + 255) / 256, 256, 0, stream>>>(Wmat, scale_w, wq);
    k_main<<<B_ROWS, 1024, 0, stream>>>(x, wq, bias, scale_w, out);
}